// Round 3
// baseline (39436.490 us; speedup 1.0000x reference)
//
#include <hip/hip_runtime.h>
#include <hip/hip_bf16.h>
#include <math.h>

#define BB   64
#define HH   56
#define WWD  56
#define CCH  96
#define NHH  3
#define WSS  7
#define SSS  3
#define HIDD 384
#define NTK  49      // tokens per window
#define NWIN 64      // windows per image
#define HDD  32      // head dim
#define TOKENS (BB*HH*WWD)   // 200704
#define QKP  98      // padded bf16 row stride (odd word stride -> no LDS bank conflicts)

__device__ __forceinline__ float b2f(__hip_bfloat16 v) { return __bfloat162float(v); }

// Input dtype flag: 1 = buffers are float32, 0 = bf16. Written by detect_kernel
// each launch (deterministic), read by later kernels (stream-ordered).
__device__ int g_in_f32;

__device__ __forceinline__ float ldin(const void* p, size_t i, int f32) {
    return f32 ? ((const float*)p)[i]
               : __bfloat162float(((const __hip_bfloat16*)p)[i]);
}

// ---------------------------------------------------------------------------
// Kernel 0: detect dtype by scanning x's u16 halves for bf16 NaN/Inf patterns.
// fp32 random data: low-half u16s hit (u&0x7F80)==0x7F80 at ~0.4% rate.
// True bf16 normal data: never.
// ---------------------------------------------------------------------------
__global__ __launch_bounds__(256) void detect_kernel(const unsigned short* __restrict__ x) {
    __shared__ int cnt;
    if (threadIdx.x == 0) cnt = 0;
    __syncthreads();
    int local = 0;
    for (int i = threadIdx.x; i < 16384; i += 256) {
        unsigned short u = x[i];
        if ((u & 0x7F80) == 0x7F80) local++;
    }
    atomicAdd(&cnt, local);
    __syncthreads();
    if (threadIdx.x == 0) g_in_f32 = (cnt > 4) ? 1 : 0;
}

// ---------------------------------------------------------------------------
// Kernel A: LN1 + shifted-window attention + proj + residual, one block/window
// ---------------------------------------------------------------------------
__global__ __launch_bounds__(256) void attn_kernel(
    const void* __restrict__ x,
    const void* __restrict__ n1g, const void* __restrict__ n1b,
    const void* __restrict__ qkv_w, const void* __restrict__ qkv_b,
    const void* __restrict__ rpb,
    const void* __restrict__ proj_w, const void* __restrict__ proj_b,
    float* __restrict__ xr32, void* __restrict__ outv, int use32)
{
    __shared__ float xw[NTK][CCH];            // LN'd input, later attn-out
    __shared__ __hip_bfloat16 qs[NTK][QKP];   // scaled q
    __shared__ __hip_bfloat16 ks[NTK][QKP];
    __shared__ __hip_bfloat16 vs[NTK][QKP];
    __shared__ float sc[NTK][NTK];            // one head's scores

    const int f32 = g_in_f32;
    const int wgid = blockIdx.x;
    const int b  = wgid >> 6;
    const int wy = (wgid >> 3) & 7;
    const int wx = wgid & 7;
    const int tid  = threadIdx.x;
    const int lane = tid & 63;
    const int wv   = tid >> 6;

    // ---- load + LN1 (one wave per token; lane covers ch {lane, lane+64}) ----
    for (int t = wv; t < NTK; t += 4) {
        int yi = t / 7, xi = t % 7;
        int r = wy * 7 + yi + SSS; if (r >= HH)  r -= HH;
        int c = wx * 7 + xi + SSS; if (c >= WWD) c -= WWD;
        size_t base = ((size_t)(b * HH + r) * WWD + c) * CCH;
        float v0 = ldin(x, base + lane, f32);
        float v1 = (lane < 32) ? ldin(x, base + 64 + lane, f32) : 0.f;
        float s = v0 + v1;
        #pragma unroll
        for (int o = 32; o; o >>= 1) s += __shfl_down(s, o);
        s = __shfl(s, 0);
        float mean = s * (1.f / 96.f);
        float d0 = v0 - mean;
        float d1 = (lane < 32) ? (v1 - mean) : 0.f;
        float q = d0 * d0 + d1 * d1;
        #pragma unroll
        for (int o = 32; o; o >>= 1) q += __shfl_down(q, o);
        q = __shfl(q, 0);
        float rstd = rsqrtf(q * (1.f / 96.f) + 1e-5f);
        xw[t][lane] = d0 * rstd * ldin(n1g, lane, f32) + ldin(n1b, lane, f32);
        if (lane < 32)
            xw[t][64 + lane] = d1 * rstd * ldin(n1g, 64 + lane, f32) + ldin(n1b, 64 + lane, f32);
    }
    __syncthreads();

    // ---- QKV projection: 49 x 288 outputs, dot over 96 ----
    for (int idx = tid; idx < NTK * 288; idx += 256) {
        int t = idx / 288, oc = idx % 288;
        size_t wbase = (size_t)oc * 96;
        float s = 0.f;
        #pragma unroll
        for (int k = 0; k < 96; ++k) s += xw[t][k] * ldin(qkv_w, wbase + k, f32);
        s += ldin(qkv_b, oc, f32);
        if (oc < 96)       qs[t][oc]       = __float2bfloat16(s * 0.17677669529663687f);
        else if (oc < 192) ks[t][oc - 96]  = __float2bfloat16(s);
        else               vs[t][oc - 192] = __float2bfloat16(s);
    }
    __syncthreads();

    // ---- per-head attention ----
    for (int h = 0; h < NHH; ++h) {
        const int hb = h * 32;
        for (int idx = tid; idx < NTK * NTK; idx += 256) {
            int i = idx / NTK, j = idx % NTK;
            int yi = i / 7, xi = i % 7, yj = j / 7, xj = j % 7;
            float s = 0.f;
            #pragma unroll
            for (int d = 0; d < 32; ++d) s += b2f(qs[i][hb + d]) * b2f(ks[j][hb + d]);
            int ridx = (yi - yj + 6) * 13 + (xi - xj + 6);
            s += ldin(rpb, (size_t)ridx * 3 + h, f32);
            int ri = wy * 7 + yi, ci = wx * 7 + xi;
            int rj = wy * 7 + yj, cj = wx * 7 + xj;
            int li = (ri < 49 ? 0 : (ri < 53 ? 1 : 2)) * 3 + (ci < 49 ? 0 : (ci < 53 ? 1 : 2));
            int lj = (rj < 49 ? 0 : (rj < 53 ? 1 : 2)) * 3 + (cj < 49 ? 0 : (cj < 53 ? 1 : 2));
            if (li != lj) s -= 100.f;
            sc[i][j] = s;
        }
        __syncthreads();
        if (tid < NTK) {
            const int i = tid;
            float m = -1e30f;
            for (int j = 0; j < NTK; ++j) m = fmaxf(m, sc[i][j]);
            float sum = 0.f;
            for (int j = 0; j < NTK; ++j) { float e = __expf(sc[i][j] - m); sc[i][j] = e; sum += e; }
            float inv = 1.f / sum;
            for (int j = 0; j < NTK; ++j) sc[i][j] *= inv;
        }
        __syncthreads();
        for (int idx = tid; idx < NTK * 32; idx += 256) {
            int i = idx >> 5, d = idx & 31;
            float s = 0.f;
            for (int j = 0; j < NTK; ++j) s += sc[i][j] * b2f(vs[j][hb + d]);
            xw[i][hb + d] = s;
        }
        __syncthreads();
    }

    // ---- proj + residual + write xr (window-reverse + un-shift == same loc) ----
    for (int idx = tid; idx < NTK * 96; idx += 256) {
        int t = idx / 96, c2 = idx % 96;
        size_t wbase = (size_t)c2 * 96;
        float s = 0.f;
        #pragma unroll
        for (int k = 0; k < 96; ++k) s += xw[t][k] * ldin(proj_w, wbase + k, f32);
        s += ldin(proj_b, c2, f32);
        int yi = t / 7, xi = t % 7;
        int r = wy * 7 + yi + SSS; if (r >= HH)  r -= HH;
        int c = wx * 7 + xi + SSS; if (c >= WWD) c -= WWD;
        size_t gi = ((size_t)(b * HH + r) * WWD + c) * CCH + c2;
        s += ldin(x, gi, f32);
        if (use32)      xr32[gi] = s;
        else if (f32)   ((float*)outv)[gi] = s;
        else            ((__hip_bfloat16*)outv)[gi] = __float2bfloat16(s);
    }
}

// ---------------------------------------------------------------------------
// Kernel B: LN2 + MLP (96 -> 384 -> 96, erf GELU) + residual, 32 tokens/block
// ---------------------------------------------------------------------------
#define TT 32
__global__ __launch_bounds__(256) void mlp_kernel(
    const float* __restrict__ xr32, int use32,
    const void* __restrict__ n2g, const void* __restrict__ n2b,
    const void* __restrict__ fc1_w, const void* __restrict__ fc1_b,
    const void* __restrict__ fc2_w, const void* __restrict__ fc2_b,
    void* __restrict__ outv)
{
    __shared__ float hbuf[TT][CCH];
    __shared__ __hip_bfloat16 act[TT][HIDD];
    const int f32 = g_in_f32;
    const int t0  = blockIdx.x * TT;
    const int tid = threadIdx.x, lane = tid & 63, wv = tid >> 6;

    // residual loader: staged in ws (fp32) or in out-buffer (out dtype)
    auto ldxr = [&](size_t i) -> float {
        if (use32) return xr32[i];
        if (f32)   return ((const float*)outv)[i];
        return b2f(((const __hip_bfloat16*)outv)[i]);
    };

    // LN2
    for (int t = wv; t < TT; t += 4) {
        size_t base = (size_t)(t0 + t) * CCH;
        float v0 = ldxr(base + lane);
        float v1 = (lane < 32) ? ldxr(base + 64 + lane) : 0.f;
        float s = v0 + v1;
        #pragma unroll
        for (int o = 32; o; o >>= 1) s += __shfl_down(s, o);
        s = __shfl(s, 0);
        float mean = s * (1.f / 96.f);
        float d0 = v0 - mean;
        float d1 = (lane < 32) ? (v1 - mean) : 0.f;
        float q = d0 * d0 + d1 * d1;
        #pragma unroll
        for (int o = 32; o; o >>= 1) q += __shfl_down(q, o);
        q = __shfl(q, 0);
        float rstd = rsqrtf(q * (1.f / 96.f) + 1e-5f);
        hbuf[t][lane] = d0 * rstd * ldin(n2g, lane, f32) + ldin(n2b, lane, f32);
        if (lane < 32)
            hbuf[t][64 + lane] = d1 * rstd * ldin(n2g, 64 + lane, f32) + ldin(n2b, 64 + lane, f32);
    }
    __syncthreads();

    // fc1 + GELU(erf)
    for (int idx = tid; idx < TT * HIDD; idx += 256) {
        int t = idx / HIDD, o = idx % HIDD;
        size_t wbase = (size_t)o * 96;
        float s = 0.f;
        #pragma unroll
        for (int k = 0; k < 96; ++k) s += hbuf[t][k] * ldin(fc1_w, wbase + k, f32);
        s += ldin(fc1_b, o, f32);
        float g = 0.5f * s * (1.f + erff(s * 0.70710678118654752f));
        act[t][o] = __float2bfloat16(g);
    }
    __syncthreads();

    // fc2 + residual (each gi read+written by exactly one thread -> alias-safe)
    for (int idx = tid; idx < TT * CCH; idx += 256) {
        int t = idx / CCH, c = idx % CCH;
        size_t wbase = (size_t)c * HIDD;
        float s = 0.f;
        #pragma unroll 4
        for (int k = 0; k < HIDD; ++k) s += b2f(act[t][k]) * ldin(fc2_w, wbase + k, f32);
        s += ldin(fc2_b, c, f32);
        size_t gi = (size_t)(t0 + t) * CCH + c;
        float r = ldxr(gi);
        float o = r + s;
        if (f32) ((float*)outv)[gi] = o;
        else     ((__hip_bfloat16*)outv)[gi] = __float2bfloat16(o);
    }
}

// ---------------------------------------------------------------------------
extern "C" void kernel_launch(void* const* d_in, const int* in_sizes, int n_in,
                              void* d_out, int out_size, void* d_ws, size_t ws_size,
                              hipStream_t stream) {
    const void* x      = d_in[0];
    const void* n1g    = d_in[1];
    const void* n1b    = d_in[2];
    const void* qkv_w  = d_in[3];
    const void* qkv_b  = d_in[4];
    const void* rpb    = d_in[5];
    const void* proj_w = d_in[6];
    const void* proj_b = d_in[7];
    const void* n2g    = d_in[8];
    const void* n2b    = d_in[9];
    const void* fc1_w  = d_in[10];
    const void* fc1_b  = d_in[11];
    const void* fc2_w  = d_in[12];
    const void* fc2_b  = d_in[13];

    const size_t need = (size_t)TOKENS * CCH * sizeof(float);
    const int use32 = (ws_size >= need) ? 1 : 0;
    float* xr32 = (float*)d_ws;

    detect_kernel<<<1, 256, 0, stream>>>((const unsigned short*)d_in[0]);
    attn_kernel<<<BB * NWIN, 256, 0, stream>>>(
        x, n1g, n1b, qkv_w, qkv_b, rpb, proj_w, proj_b, xr32, d_out, use32);
    mlp_kernel<<<TOKENS / TT, 256, 0, stream>>>(
        xr32, use32, n2g, n2b, fc1_w, fc1_b, fc2_w, fc2_b, d_out);
}

// Round 4
// 746.751 us; speedup vs baseline: 52.8108x; 52.8108x over previous
//
#include <hip/hip_runtime.h>
#include <math.h>

#define BB   64
#define HH   56
#define WWD  56
#define CCH  96
#define NHH  3
#define WSS  7
#define SSS  3
#define HIDD 384
#define NTK  49
#define TOKENS (BB*HH*WWD)   // 200704

typedef unsigned short ushort;
typedef short short8 __attribute__((ext_vector_type(8)));
typedef float floatx4 __attribute__((ext_vector_type(4)));

__device__ __forceinline__ ushort f2bf(float f) {
    union { float f; unsigned u; } v; v.f = f;
    unsigned r = v.u + 0x7FFF + ((v.u >> 16) & 1);
    return (ushort)(r >> 16);
}
__device__ __forceinline__ float bf2f(ushort h) {
    union { unsigned u; float f; } v; v.u = ((unsigned)h) << 16;
    return v.f;
}

// weight offsets (elements) inside ws bf16 arena
#define WOFF_QKV  0
#define WOFF_PROJ 27648
#define WOFF_FC1  36864
#define WOFF_FC2  73728
#define WTOTAL    110592

// ---------------------------------------------------------------------------
// Convert fp32 weights -> bf16 arena in ws (re-run every launch; ws re-poisoned)
// ---------------------------------------------------------------------------
__global__ __launch_bounds__(256) void wconv(
    const float* __restrict__ qkv_w, const float* __restrict__ proj_w,
    const float* __restrict__ fc1_w, const float* __restrict__ fc2_w,
    ushort* __restrict__ wsb)
{
    int i = blockIdx.x * 256 + threadIdx.x;
    if (i >= WTOTAL) return;
    float v;
    if      (i < WOFF_PROJ) v = qkv_w[i - WOFF_QKV];
    else if (i < WOFF_FC1)  v = proj_w[i - WOFF_PROJ];
    else if (i < WOFF_FC2)  v = fc1_w[i - WOFF_FC1];
    else                    v = fc2_w[i - WOFF_FC2];
    wsb[i] = f2bf(v);
}

// ---------------------------------------------------------------------------
// Attention: one block per (batch, window). LN1 -> QKV -> per-head
// scores+softmax(+bias+mask) -> PV -> proj + residual -> xr (fp32 in d_out).
// ---------------------------------------------------------------------------
__global__ __launch_bounds__(256) void attn_kernel(
    const float* __restrict__ x,
    const float* __restrict__ n1g, const float* __restrict__ n1b,
    const ushort* __restrict__ wsb,
    const float* __restrict__ qkv_b, const float* __restrict__ rpb,
    const float* __restrict__ proj_b,
    float* __restrict__ xr)
{
    __shared__ ushort xa[64][104];   // LN1 out (A for QKV); later attn-out (A for proj)
    __shared__ ushort qs[64][104];   // q (pre-scaled), [token][ch]
    __shared__ ushort ks[64][104];   // k, [token][ch]
    __shared__ ushort vt[96][72];    // v transposed, [ch][token]
    __shared__ ushort ps[64][72];    // softmax probs, [row token][col token]

    const int wgid = blockIdx.x;
    const int b  = wgid >> 6;
    const int wy = (wgid >> 3) & 7;
    const int wx = wgid & 7;
    const int tid  = threadIdx.x;
    const int lane = tid & 63;
    const int wv   = tid >> 6;
    const int l15  = lane & 15;
    const int quad = lane >> 4;
    const int m0   = wv * 16;

    const ushort* wq = wsb + WOFF_QKV;
    const ushort* wp = wsb + WOFF_PROJ;

    // ---- LN1 into xa (bf16); one wave per token ----
    for (int t = wv; t < NTK; t += 4) {
        int yi = t / 7, xi = t % 7;
        int r = wy * 7 + yi + SSS; if (r >= HH)  r -= HH;
        int c = wx * 7 + xi + SSS; if (c >= WWD) c -= WWD;
        const float* px = x + ((size_t)(b * HH + r) * WWD + c) * CCH;
        float v0 = px[lane];
        float v1 = (lane < 32) ? px[64 + lane] : 0.f;
        float s = v0 + v1;
        #pragma unroll
        for (int o = 32; o; o >>= 1) s += __shfl_down(s, o);
        s = __shfl(s, 0);
        float mean = s * (1.f / 96.f);
        float d0 = v0 - mean;
        float d1 = (lane < 32) ? (v1 - mean) : 0.f;
        float q = d0 * d0 + d1 * d1;
        #pragma unroll
        for (int o = 32; o; o >>= 1) q += __shfl_down(q, o);
        q = __shfl(q, 0);
        float rstd = rsqrtf(q * (1.f / 96.f) + 1e-5f);
        xa[t][lane] = f2bf(d0 * rstd * n1g[lane] + n1b[lane]);
        if (lane < 32)
            xa[t][64 + lane] = f2bf(d1 * rstd * n1g[64 + lane] + n1b[64 + lane]);
    }
    // zero pad rows 49..63
    for (int t = 49 + wv; t < 64; t += 4) {
        xa[t][lane] = 0;
        if (lane < 32) xa[t][64 + lane] = 0;
    }
    __syncthreads();

    // ---- QKV: wave computes rows m0..m0+15 x all 288 out-channels ----
    for (int ct = 0; ct < 18; ++ct) {
        floatx4 acc = {0.f, 0.f, 0.f, 0.f};
        #pragma unroll
        for (int kt = 0; kt < 3; ++kt) {
            short8 a = *(const short8*)&xa[m0 + l15][kt * 32 + quad * 8];
            short8 bw = *(const short8*)(wq + (size_t)(ct * 16 + l15) * 96 + kt * 32 + quad * 8);
            acc = __builtin_amdgcn_mfma_f32_16x16x32_bf16(a, bw, acc, 0, 0, 0);
        }
        int oc = ct * 16 + l15;
        float bias = qkv_b[oc];
        #pragma unroll
        for (int r = 0; r < 4; ++r) {
            int m = m0 + quad * 4 + r;
            float v = acc[r] + bias;
            if (oc < 96)       qs[m][oc]        = f2bf(v * 0.17677669529663687f);
            else if (oc < 192) ks[m][oc - 96]   = f2bf(v);
            else               vt[oc - 192][m]  = f2bf(v);
        }
    }
    __syncthreads();

    // ---- per-head: scores (+bias+mask) -> softmax in-register -> PV ----
    // per-row geometry for this wave's 4x4-row ownership
    int rowm[4], rowli[4], rowy[4], rowx[4];
    #pragma unroll
    for (int r = 0; r < 4; ++r) {
        int m = m0 + quad * 4 + r;
        rowm[r] = m;
        int yi = m / 7, xi = m - 7 * yi;
        rowy[r] = yi; rowx[r] = xi;
        int ri = wy * 7 + yi, ci = wx * 7 + xi;
        rowli[r] = (ri < 49 ? 0 : (ri < 53 ? 1 : 2)) * 3 + (ci < 49 ? 0 : (ci < 53 ? 1 : 2));
    }

    for (int h = 0; h < NHH; ++h) {
        const int hb = 32 * h;
        float sc0[4][4];  // [col-tile][reg]
        short8 aq = *(const short8*)&qs[m0 + l15][hb + quad * 8];
        #pragma unroll
        for (int ct = 0; ct < 4; ++ct) {
            short8 bk = *(const short8*)&ks[ct * 16 + l15][hb + quad * 8];
            floatx4 acc = {0.f, 0.f, 0.f, 0.f};
            acc = __builtin_amdgcn_mfma_f32_16x16x32_bf16(aq, bk, acc, 0, 0, 0);
            #pragma unroll
            for (int r = 0; r < 4; ++r) sc0[ct][r] = acc[r];
        }
        // bias + mask
        #pragma unroll
        for (int ct = 0; ct < 4; ++ct) {
            int cj = ct * 16 + l15;
            if (cj >= NTK) {
                #pragma unroll
                for (int r = 0; r < 4; ++r) sc0[ct][r] = -1e30f;
            } else {
                int yj = cj / 7, xj = cj - 7 * yj;
                int rj = wy * 7 + yj, cjc = wx * 7 + xj;
                int lj = (rj < 49 ? 0 : (rj < 53 ? 1 : 2)) * 3 + (cjc < 49 ? 0 : (cjc < 53 ? 1 : 2));
                #pragma unroll
                for (int r = 0; r < 4; ++r) {
                    if (rowm[r] >= NTK) { sc0[ct][r] = -1e30f; continue; }
                    int ridx = (rowy[r] - yj + 6) * 13 + (rowx[r] - xj + 6);
                    float s = sc0[ct][r] + rpb[ridx * 3 + h];
                    if (rowli[r] != lj) s -= 100.f;
                    sc0[ct][r] = s;
                }
            }
        }
        // softmax per row (rows live in this 16-lane quad-group)
        #pragma unroll
        for (int r = 0; r < 4; ++r) {
            float mx = fmaxf(fmaxf(sc0[0][r], sc0[1][r]), fmaxf(sc0[2][r], sc0[3][r]));
            #pragma unroll
            for (int o = 1; o < 16; o <<= 1) mx = fmaxf(mx, __shfl_xor(mx, o));
            float sum = 0.f;
            #pragma unroll
            for (int ct = 0; ct < 4; ++ct) { float e = __expf(sc0[ct][r] - mx); sc0[ct][r] = e; sum += e; }
            #pragma unroll
            for (int o = 1; o < 16; o <<= 1) sum += __shfl_xor(sum, o);
            float inv = 1.f / sum;
            #pragma unroll
            for (int ct = 0; ct < 4; ++ct)
                ps[rowm[r]][ct * 16 + l15] = f2bf(sc0[ct][r] * inv);
        }
        // PV: D[16 x 32] for this head
        short8 ap0 = *(const short8*)&ps[m0 + l15][quad * 8];
        short8 ap1 = *(const short8*)&ps[m0 + l15][32 + quad * 8];
        #pragma unroll
        for (int nt = 0; nt < 2; ++nt) {
            floatx4 acc = {0.f, 0.f, 0.f, 0.f};
            short8 bv0 = *(const short8*)&vt[hb + nt * 16 + l15][quad * 8];
            short8 bv1 = *(const short8*)&vt[hb + nt * 16 + l15][32 + quad * 8];
            acc = __builtin_amdgcn_mfma_f32_16x16x32_bf16(ap0, bv0, acc, 0, 0, 0);
            acc = __builtin_amdgcn_mfma_f32_16x16x32_bf16(ap1, bv1, acc, 0, 0, 0);
            #pragma unroll
            for (int r = 0; r < 4; ++r)
                xa[m0 + quad * 4 + r][hb + nt * 16 + l15] = f2bf(acc[r]);
        }
    }

    // ---- proj + bias + residual -> xr (fp32) ----
    for (int ct = 0; ct < 6; ++ct) {
        floatx4 acc = {0.f, 0.f, 0.f, 0.f};
        #pragma unroll
        for (int kt = 0; kt < 3; ++kt) {
            short8 a = *(const short8*)&xa[m0 + l15][kt * 32 + quad * 8];
            short8 bw = *(const short8*)(wp + (size_t)(ct * 16 + l15) * 96 + kt * 32 + quad * 8);
            acc = __builtin_amdgcn_mfma_f32_16x16x32_bf16(a, bw, acc, 0, 0, 0);
        }
        int c2 = ct * 16 + l15;
        float pb = proj_b[c2];
        #pragma unroll
        for (int r = 0; r < 4; ++r) {
            int m = m0 + quad * 4 + r;
            if (m >= NTK) continue;
            int yi = rowy[r], xi = rowx[r];
            int rr = wy * 7 + yi + SSS; if (rr >= HH)  rr -= HH;
            int cc = wx * 7 + xi + SSS; if (cc >= WWD) cc -= WWD;
            size_t gi = ((size_t)(b * HH + rr) * WWD + cc) * CCH + c2;
            xr[gi] = acc[r] + pb + x[gi];
        }
    }
}

// ---------------------------------------------------------------------------
// MLP: 64 tokens/block. LN2 -> fc1+GELU(erf) -> fc2 + residual, in-place d_out.
// ---------------------------------------------------------------------------
__global__ __launch_bounds__(256) void mlp_kernel(
    const float* __restrict__ n2g, const float* __restrict__ n2b,
    const ushort* __restrict__ wsb,
    const float* __restrict__ fc1_b, const float* __restrict__ fc2_b,
    float* __restrict__ xr)   // = d_out, in-place update
{
    __shared__ ushort xn[64][104];    // LN2 out
    __shared__ ushort act[64][392];   // fc1+GELU out

    const int t0   = blockIdx.x * 64;
    const int tid  = threadIdx.x;
    const int lane = tid & 63;
    const int wv   = tid >> 6;
    const int l15  = lane & 15;
    const int quad = lane >> 4;
    const int m0   = wv * 16;

    const ushort* w1 = wsb + WOFF_FC1;
    const ushort* w2 = wsb + WOFF_FC2;

    // ---- LN2 ----
    for (int t = wv; t < 64; t += 4) {
        const float* px = xr + (size_t)(t0 + t) * CCH;
        float v0 = px[lane];
        float v1 = (lane < 32) ? px[64 + lane] : 0.f;
        float s = v0 + v1;
        #pragma unroll
        for (int o = 32; o; o >>= 1) s += __shfl_down(s, o);
        s = __shfl(s, 0);
        float mean = s * (1.f / 96.f);
        float d0 = v0 - mean;
        float d1 = (lane < 32) ? (v1 - mean) : 0.f;
        float q = d0 * d0 + d1 * d1;
        #pragma unroll
        for (int o = 32; o; o >>= 1) q += __shfl_down(q, o);
        q = __shfl(q, 0);
        float rstd = rsqrtf(q * (1.f / 96.f) + 1e-5f);
        xn[t][lane] = f2bf(d0 * rstd * n2g[lane] + n2b[lane]);
        if (lane < 32)
            xn[t][64 + lane] = f2bf(d1 * rstd * n2g[64 + lane] + n2b[64 + lane]);
    }
    __syncthreads();

    // ---- fc1 + GELU(erf) ----
    for (int ct = 0; ct < 24; ++ct) {
        floatx4 acc = {0.f, 0.f, 0.f, 0.f};
        #pragma unroll
        for (int kt = 0; kt < 3; ++kt) {
            short8 a = *(const short8*)&xn[m0 + l15][kt * 32 + quad * 8];
            short8 bw = *(const short8*)(w1 + (size_t)(ct * 16 + l15) * 96 + kt * 32 + quad * 8);
            acc = __builtin_amdgcn_mfma_f32_16x16x32_bf16(a, bw, acc, 0, 0, 0);
        }
        int oc = ct * 16 + l15;
        float b1 = fc1_b[oc];
        #pragma unroll
        for (int r = 0; r < 4; ++r) {
            float v = acc[r] + b1;
            float g = 0.5f * v * (1.f + erff(v * 0.70710678118654752f));
            act[m0 + quad * 4 + r][oc] = f2bf(g);
        }
    }

    // ---- fc2 + bias + residual (wave-private rows; act RAW is wave-internal) ----
    for (int ct = 0; ct < 6; ++ct) {
        floatx4 acc = {0.f, 0.f, 0.f, 0.f};
        #pragma unroll
        for (int kt = 0; kt < 12; ++kt) {
            short8 a = *(const short8*)&act[m0 + l15][kt * 32 + quad * 8];
            short8 bw = *(const short8*)(w2 + (size_t)(ct * 16 + l15) * 384 + kt * 32 + quad * 8);
            acc = __builtin_amdgcn_mfma_f32_16x16x32_bf16(a, bw, acc, 0, 0, 0);
        }
        int c = ct * 16 + l15;
        float b2 = fc2_b[c];
        #pragma unroll
        for (int r = 0; r < 4; ++r) {
            size_t gi = (size_t)(t0 + m0 + quad * 4 + r) * CCH + c;
            xr[gi] = xr[gi] + acc[r] + b2;
        }
    }
}

// ---------------------------------------------------------------------------
extern "C" void kernel_launch(void* const* d_in, const int* in_sizes, int n_in,
                              void* d_out, int out_size, void* d_ws, size_t ws_size,
                              hipStream_t stream) {
    const float* x      = (const float*)d_in[0];
    const float* n1g    = (const float*)d_in[1];
    const float* n1b    = (const float*)d_in[2];
    const float* qkv_w  = (const float*)d_in[3];
    const float* qkv_b  = (const float*)d_in[4];
    const float* rpb    = (const float*)d_in[5];
    const float* proj_w = (const float*)d_in[6];
    const float* proj_b = (const float*)d_in[7];
    const float* n2g    = (const float*)d_in[8];
    const float* n2b    = (const float*)d_in[9];
    const float* fc1_w  = (const float*)d_in[10];
    const float* fc1_b  = (const float*)d_in[11];
    const float* fc2_w  = (const float*)d_in[12];
    const float* fc2_b  = (const float*)d_in[13];
    float* xr = (float*)d_out;
    ushort* wsb = (ushort*)d_ws;

    wconv<<<(WTOTAL + 255) / 256, 256, 0, stream>>>(qkv_w, proj_w, fc1_w, fc2_w, wsb);
    attn_kernel<<<BB * 64, 256, 0, stream>>>(x, n1g, n1b, wsb, qkv_b, rpb, proj_b, xr);
    mlp_kernel<<<TOKENS / 64, 256, 0, stream>>>(n2g, n2b, wsb, fc1_b, fc2_b, xr);
}

// Round 5
// 478.582 us; speedup vs baseline: 82.4028x; 1.5603x over previous
//
#include <hip/hip_runtime.h>
#include <math.h>

#define BB   64
#define HH   56
#define WWD  56
#define CCH  96
#define SSS  3
#define NTK  49
#define TOKENS (BB*HH*WWD)   // 200704

typedef unsigned short ushort;
typedef short short8 __attribute__((ext_vector_type(8)));
typedef float floatx4 __attribute__((ext_vector_type(4)));

__device__ __forceinline__ ushort f2bf(float f) {
    union { float f; unsigned u; } v; v.f = f;
    unsigned r = v.u + 0x7FFF + ((v.u >> 16) & 1);
    return (ushort)(r >> 16);
}

// bf16 B-fragment arena in ws: frag = 64 lanes x 8 shorts = 512 shorts.
// qkv: frag (ct*3+kt), ct<18; proj: +54, ct<6; fc1: +72, ct<24; fc2: +144, ct*12+hc.
#define WQKV  0
#define WPROJ (54*512)
#define WFC1  (72*512)
#define WFC2  (144*512)
#define NFRAG 216

// ---------------------------------------------------------------------------
// Weight convert + swizzle: each thread = one (frag, lane) -> 8 bf16, coalesced.
// ---------------------------------------------------------------------------
__global__ __launch_bounds__(256) void wconv(
    const float* __restrict__ qkv_w, const float* __restrict__ proj_w,
    const float* __restrict__ fc1_w, const float* __restrict__ fc2_w,
    ushort* __restrict__ wsb)
{
    int tg = blockIdx.x * 256 + threadIdx.x;
    int frag = tg >> 6, lane = tg & 63, l15 = lane & 15, quad = lane >> 4;
    const float* src; int row, kbase, K;
    if (frag < 54)       { int f = frag;       int ct = f/3,  kt = f%3;  src = qkv_w;  row = ct*16+l15; kbase = kt*32+quad*8; K = 96;  }
    else if (frag < 72)  { int f = frag - 54;  int ct = f/3,  kt = f%3;  src = proj_w; row = ct*16+l15; kbase = kt*32+quad*8; K = 96;  }
    else if (frag < 144) { int f = frag - 72;  int ct = f/3,  kt = f%3;  src = fc1_w;  row = ct*16+l15; kbase = kt*32+quad*8; K = 96;  }
    else                 { int f = frag - 144; int ct = f/12, hc = f%12; src = fc2_w;  row = ct*16+l15; kbase = hc*32+quad*8; K = 384; }
    const float* p = src + (size_t)row * K + kbase;
    ushort tmp[8];
    #pragma unroll
    for (int j = 0; j < 8; ++j) tmp[j] = f2bf(p[j]);
    *(short8*)(wsb + (size_t)frag * 512 + lane * 8) = *(const short8*)tmp;
}

// ---------------------------------------------------------------------------
// Fused Swin block: LN1 -> QKV -> attn (bias+mask+softmax) -> proj+residual
// -> LN2 -> fc1+GELU -> fc2 + residual -> out.  One block per (batch,window).
// ---------------------------------------------------------------------------
__global__ __launch_bounds__(256) void swin_kernel(
    const float* __restrict__ x,
    const float* __restrict__ n1g, const float* __restrict__ n1b,
    const ushort* __restrict__ wsb,
    const float* __restrict__ qkv_b, const float* __restrict__ rpb,
    const float* __restrict__ proj_b,
    const float* __restrict__ n2g, const float* __restrict__ n2b,
    const float* __restrict__ fc1_b, const float* __restrict__ fc2_b,
    float* __restrict__ out)
{
    __shared__ ushort xa[64][104];   // LN1-out -> q-scratch -> attn-out -> LN2-out
    __shared__ float  kvf[6592];     // ks[64][104] ++ vt[96][68]; later xrbuf fp32 stride 100
    __shared__ ushort ps[64][72];    // probs (wave-private); later act chunks [4][16][40]
    __shared__ float  rpbs[507];

    ushort (*ks)[104] = (ushort(*)[104])kvf;
    ushort (*vt)[68]  = (ushort(*)[68])((ushort*)kvf + 64*104);
    float* xrbuf = kvf;              // [64][100] fp32, valid after barrier #2

    const int wgid = blockIdx.x;
    const int b  = wgid >> 6;
    const int wy = (wgid >> 3) & 7;
    const int wx = wgid & 7;
    const int tid  = threadIdx.x;
    const int lane = tid & 63;
    const int wv   = tid >> 6;
    const int l15  = lane & 15;
    const int quad = lane >> 4;
    const int m0   = wv * 16;

    for (int i = tid; i < 507; i += 256) rpbs[i] = rpb[i];

    // ---- LN1: wave owns rows m0..m0+15 (pad rows zeroed) ----
    {
        float g0 = n1g[lane], bb0 = n1b[lane];
        float g1 = (lane < 32) ? n1g[64 + lane] : 0.f;
        float bb1 = (lane < 32) ? n1b[64 + lane] : 0.f;
        for (int r16 = 0; r16 < 16; ++r16) {
            int t = m0 + r16;
            if (t < NTK) {
                int yi = t / 7, xi = t % 7;
                int rr = wy * 7 + yi + SSS; if (rr >= HH)  rr -= HH;
                int cc = wx * 7 + xi + SSS; if (cc >= WWD) cc -= WWD;
                const float* px = x + ((size_t)(b * HH + rr) * WWD + cc) * CCH;
                float v0 = px[lane];
                float v1 = (lane < 32) ? px[64 + lane] : 0.f;
                float s = v0 + v1;
                #pragma unroll
                for (int o = 32; o; o >>= 1) s += __shfl_down(s, o);
                s = __shfl(s, 0);
                float mean = s * (1.f / 96.f);
                float d0 = v0 - mean;
                float d1 = (lane < 32) ? (v1 - mean) : 0.f;
                float q = d0 * d0 + d1 * d1;
                #pragma unroll
                for (int o = 32; o; o >>= 1) q += __shfl_down(q, o);
                q = __shfl(q, 0);
                float rstd = rsqrtf(q * (1.f / 96.f) + 1e-5f);
                xa[t][lane] = f2bf(d0 * rstd * g0 + bb0);
                if (lane < 32) xa[t][64 + lane] = f2bf(d1 * rstd * g1 + bb1);
            } else {
                xa[t][lane] = 0;
                if (lane < 32) xa[t][64 + lane] = 0;
            }
        }
    }

    // ---- QKV: wave rows x 288 cols; q -> regs, k -> ks, v -> vt ----
    float qreg[6][4];
    for (int ct = 0; ct < 18; ++ct) {
        floatx4 acc = {0.f, 0.f, 0.f, 0.f};
        #pragma unroll
        for (int kt = 0; kt < 3; ++kt) {
            short8 a  = *(const short8*)&xa[m0 + l15][kt * 32 + quad * 8];
            short8 bw = *(const short8*)(wsb + WQKV + (size_t)(ct * 3 + kt) * 512 + lane * 8);
            acc = __builtin_amdgcn_mfma_f32_16x16x32_bf16(a, bw, acc, 0, 0, 0);
        }
        int oc = ct * 16 + l15;
        float bias = qkv_b[oc];
        if (ct < 6) {
            #pragma unroll
            for (int r = 0; r < 4; ++r) qreg[ct][r] = (acc[r] + bias) * 0.17677669529663687f;
        } else if (ct < 12) {
            #pragma unroll
            for (int r = 0; r < 4; ++r) ks[m0 + quad * 4 + r][oc - 96] = f2bf(acc[r] + bias);
        } else {
            #pragma unroll
            for (int r = 0; r < 4; ++r) vt[oc - 192][m0 + quad * 4 + r] = f2bf(acc[r] + bias);
        }
    }
    // q: C-layout -> A-layout via xa scratch (wave-private), keep in regs
    #pragma unroll
    for (int ct = 0; ct < 6; ++ct)
        #pragma unroll
        for (int r = 0; r < 4; ++r)
            xa[m0 + quad * 4 + r][ct * 16 + l15] = f2bf(qreg[ct][r]);
    short8 aq[3];
    #pragma unroll
    for (int h = 0; h < 3; ++h) aq[h] = *(const short8*)&xa[m0 + l15][h * 32 + quad * 8];
    __syncthreads();   // barrier #1: ks/vt visible

    // ---- per-head attention ----
    int rowm[4], rowli[4], rowy[4], rowx[4];
    #pragma unroll
    for (int r = 0; r < 4; ++r) {
        int m = m0 + quad * 4 + r;
        rowm[r] = m;
        int yi = m / 7, xi = m - 7 * yi;
        rowy[r] = yi; rowx[r] = xi;
        int ri = wy * 7 + yi, ci = wx * 7 + xi;
        rowli[r] = (ri < 49 ? 0 : (ri < 53 ? 1 : 2)) * 3 + (ci < 49 ? 0 : (ci < 53 ? 1 : 2));
    }

    for (int h = 0; h < 3; ++h) {
        const int hb = 32 * h;
        float sc0[4][4];
        #pragma unroll
        for (int ct = 0; ct < 4; ++ct) {
            short8 bk = *(const short8*)&ks[ct * 16 + l15][hb + quad * 8];
            floatx4 acc = {0.f, 0.f, 0.f, 0.f};
            acc = __builtin_amdgcn_mfma_f32_16x16x32_bf16(aq[h], bk, acc, 0, 0, 0);
            #pragma unroll
            for (int r = 0; r < 4; ++r) sc0[ct][r] = acc[r];
        }
        #pragma unroll
        for (int ct = 0; ct < 4; ++ct) {
            int cj = ct * 16 + l15;
            if (cj >= NTK) {
                #pragma unroll
                for (int r = 0; r < 4; ++r) sc0[ct][r] = -1e30f;
            } else {
                int yj = cj / 7, xj = cj - 7 * yj;
                int rj = wy * 7 + yj, cjc = wx * 7 + xj;
                int lj = (rj < 49 ? 0 : (rj < 53 ? 1 : 2)) * 3 + (cjc < 49 ? 0 : (cjc < 53 ? 1 : 2));
                #pragma unroll
                for (int r = 0; r < 4; ++r) {
                    if (rowm[r] >= NTK) { sc0[ct][r] = -1e30f; continue; }
                    int ridx = (rowy[r] - yj + 6) * 13 + (rowx[r] - xj + 6);
                    float s = sc0[ct][r] + rpbs[ridx * 3 + h];
                    if (rowli[r] != lj) s -= 100.f;
                    sc0[ct][r] = s;
                }
            }
        }
        #pragma unroll
        for (int r = 0; r < 4; ++r) {
            float mx = fmaxf(fmaxf(sc0[0][r], sc0[1][r]), fmaxf(sc0[2][r], sc0[3][r]));
            #pragma unroll
            for (int o = 1; o < 16; o <<= 1) mx = fmaxf(mx, __shfl_xor(mx, o));
            float sum = 0.f;
            #pragma unroll
            for (int ct = 0; ct < 4; ++ct) { float e = __expf(sc0[ct][r] - mx); sc0[ct][r] = e; sum += e; }
            #pragma unroll
            for (int o = 1; o < 16; o <<= 1) sum += __shfl_xor(sum, o);
            float inv = 1.f / sum;
            #pragma unroll
            for (int ct = 0; ct < 4; ++ct)
                ps[rowm[r]][ct * 16 + l15] = f2bf(sc0[ct][r] * inv);
        }
        // PV
        short8 ap0 = *(const short8*)&ps[m0 + l15][quad * 8];
        short8 ap1 = *(const short8*)&ps[m0 + l15][32 + quad * 8];
        #pragma unroll
        for (int nt = 0; nt < 2; ++nt) {
            floatx4 acc = {0.f, 0.f, 0.f, 0.f};
            short8 bv0 = *(const short8*)&vt[hb + nt * 16 + l15][quad * 8];
            short8 bv1 = *(const short8*)&vt[hb + nt * 16 + l15][32 + quad * 8];
            acc = __builtin_amdgcn_mfma_f32_16x16x32_bf16(ap0, bv0, acc, 0, 0, 0);
            acc = __builtin_amdgcn_mfma_f32_16x16x32_bf16(ap1, bv1, acc, 0, 0, 0);
            #pragma unroll
            for (int r = 0; r < 4; ++r)
                xa[m0 + quad * 4 + r][hb + nt * 16 + l15] = f2bf(acc[r]);
        }
    }

    __syncthreads();   // barrier #2: everyone done with ks/vt -> reuse as xrbuf

    // ---- proj + bias + residual -> xrv regs + xrbuf ----
    float xrv[6][4];
    for (int ct = 0; ct < 6; ++ct) {
        floatx4 acc = {0.f, 0.f, 0.f, 0.f};
        #pragma unroll
        for (int kt = 0; kt < 3; ++kt) {
            short8 a  = *(const short8*)&xa[m0 + l15][kt * 32 + quad * 8];
            short8 bw = *(const short8*)(wsb + WPROJ + (size_t)(ct * 3 + kt) * 512 + lane * 8);
            acc = __builtin_amdgcn_mfma_f32_16x16x32_bf16(a, bw, acc, 0, 0, 0);
        }
        int c2 = ct * 16 + l15;
        float pb = proj_b[c2];
        #pragma unroll
        for (int r = 0; r < 4; ++r) {
            int m = m0 + quad * 4 + r;
            float v = 0.f;
            if (m < NTK) {
                int rr = wy * 7 + rowy[r] + SSS; if (rr >= HH)  rr -= HH;
                int cc = wx * 7 + rowx[r] + SSS; if (cc >= WWD) cc -= WWD;
                size_t gi = ((size_t)(b * HH + rr) * WWD + cc) * CCH + c2;
                v = acc[r] + pb + x[gi];
            }
            xrv[ct][r] = v;
            xrbuf[(m0 + quad * 4 + r) * 100 + c2] = v;
        }
    }

    // ---- LN2 in-register (row lives in this 16-lane quad group x 6 ct) ----
    float gn[6], bn[6];
    #pragma unroll
    for (int ct = 0; ct < 6; ++ct) { gn[ct] = n2g[ct * 16 + l15]; bn[ct] = n2b[ct * 16 + l15]; }
    #pragma unroll
    for (int r = 0; r < 4; ++r) {
        float s = 0.f;
        #pragma unroll
        for (int ct = 0; ct < 6; ++ct) s += xrv[ct][r];
        #pragma unroll
        for (int o = 1; o < 16; o <<= 1) s += __shfl_xor(s, o);
        float mean = s * (1.f / 96.f);
        float q = 0.f;
        #pragma unroll
        for (int ct = 0; ct < 6; ++ct) { float d = xrv[ct][r] - mean; q += d * d; }
        #pragma unroll
        for (int o = 1; o < 16; o <<= 1) q += __shfl_xor(q, o);
        float rstd = rsqrtf(q * (1.f / 96.f) + 1e-5f);
        #pragma unroll
        for (int ct = 0; ct < 6; ++ct)
            xa[m0 + quad * 4 + r][ct * 16 + l15] =
                f2bf((xrv[ct][r] - mean) * rstd * gn[ct] + bn[ct]);
    }

    // ---- MLP: fc1+GELU chunked 32-wide (wave-private act), fc2 accumulate ----
    short8 axn[3];
    #pragma unroll
    for (int kt = 0; kt < 3; ++kt) axn[kt] = *(const short8*)&xa[m0 + l15][kt * 32 + quad * 8];
    ushort (*act)[40] = (ushort(*)[40])((ushort*)ps + wv * 16 * 40);
    floatx4 o2[6];
    #pragma unroll
    for (int ct = 0; ct < 6; ++ct) o2[ct] = (floatx4){0.f, 0.f, 0.f, 0.f};

    for (int hc = 0; hc < 12; ++hc) {
        #pragma unroll
        for (int c2t = 0; c2t < 2; ++c2t) {
            floatx4 acc = {0.f, 0.f, 0.f, 0.f};
            #pragma unroll
            for (int kt = 0; kt < 3; ++kt) {
                short8 bw = *(const short8*)(wsb + WFC1 + (size_t)((hc * 2 + c2t) * 3 + kt) * 512 + lane * 8);
                acc = __builtin_amdgcn_mfma_f32_16x16x32_bf16(axn[kt], bw, acc, 0, 0, 0);
            }
            int oc = (hc * 2 + c2t) * 16 + l15;
            float b1 = fc1_b[oc];
            #pragma unroll
            for (int r = 0; r < 4; ++r) {
                float v = acc[r] + b1;
                float g = 0.5f * v * (1.f + erff(v * 0.70710678118654752f));
                act[quad * 4 + r][c2t * 16 + l15] = f2bf(g);
            }
        }
        short8 aact = *(const short8*)&act[l15][quad * 8];
        #pragma unroll
        for (int ct = 0; ct < 6; ++ct) {
            short8 bw = *(const short8*)(wsb + WFC2 + (size_t)(ct * 12 + hc) * 512 + lane * 8);
            o2[ct] = __builtin_amdgcn_mfma_f32_16x16x32_bf16(aact, bw, o2[ct], 0, 0, 0);
        }
    }

    // ---- final: out = xr + fc2 + bias ----
    for (int ct = 0; ct < 6; ++ct) {
        int c = ct * 16 + l15;
        float b2 = fc2_b[c];
        #pragma unroll
        for (int r = 0; r < 4; ++r) {
            int m = m0 + quad * 4 + r;
            if (m >= NTK) continue;
            int rr = wy * 7 + rowy[r] + SSS; if (rr >= HH)  rr -= HH;
            int cc = wx * 7 + rowx[r] + SSS; if (cc >= WWD) cc -= WWD;
            size_t gi = ((size_t)(b * HH + rr) * WWD + cc) * CCH + c;
            out[gi] = xrbuf[(m0 + quad * 4 + r) * 100 + c] + o2[ct][r] + b2;
        }
    }
}

// ---------------------------------------------------------------------------
extern "C" void kernel_launch(void* const* d_in, const int* in_sizes, int n_in,
                              void* d_out, int out_size, void* d_ws, size_t ws_size,
                              hipStream_t stream) {
    const float* x      = (const float*)d_in[0];
    const float* n1g    = (const float*)d_in[1];
    const float* n1b    = (const float*)d_in[2];
    const float* qkv_w  = (const float*)d_in[3];
    const float* qkv_b  = (const float*)d_in[4];
    const float* rpb    = (const float*)d_in[5];
    const float* proj_b = (const float*)d_in[7];
    const float* proj_w = (const float*)d_in[6];
    const float* n2g    = (const float*)d_in[8];
    const float* n2b    = (const float*)d_in[9];
    const float* fc1_w  = (const float*)d_in[10];
    const float* fc1_b  = (const float*)d_in[11];
    const float* fc2_w  = (const float*)d_in[12];
    const float* fc2_b  = (const float*)d_in[13];
    float* out = (float*)d_out;
    ushort* wsb = (ushort*)d_ws;

    wconv<<<NFRAG / 4, 256, 0, stream>>>(qkv_w, proj_w, fc1_w, fc2_w, wsb);
    swin_kernel<<<BB * 64, 256, 0, stream>>>(
        x, n1g, n1b, wsb, qkv_b, rpb, proj_b, n2g, n2b, fc1_b, fc2_b, out);
}